// Round 8
// baseline (585.954 us; speedup 1.0000x reference)
//
#include <hip/hip_runtime.h>

// Problem constants (N=8192 tokens, D=256 model dim, dropout p=0.5 -> keep scale 2.0)
#define NT 8192
#define DM 256

typedef float f32x16 __attribute__((ext_vector_type(16)));
typedef float f32x4 __attribute__((ext_vector_type(4)));
typedef __bf16 bf16x8 __attribute__((ext_vector_type(8)));
typedef unsigned int u32x4 __attribute__((ext_vector_type(4)));

#define MFMA32(a, b, c) __builtin_amdgcn_mfma_f32_32x32x16_bf16((a), (b), (c), 0, 0, 0)
#define MFMA16(a, b, c) __builtin_amdgcn_mfma_f32_16x16x32_bf16((a), (b), (c), 0, 0, 0)
#define NEG_INF (-__builtin_inff())

static __device__ __forceinline__ unsigned short f2bf_bits(float f) {
  return __builtin_bit_cast(unsigned short, (__bf16)f);
}
static __device__ __forceinline__ float exp2_fast(float x) {
  return __builtin_amdgcn_exp2f(x);
}
// async global->LDS, 16B per lane. LDS dest is wave-uniform base + lane*16.
static __device__ __forceinline__ void gload_lds16(const void* g, void* l) {
  __builtin_amdgcn_global_load_lds(
      (const __attribute__((address_space(1))) unsigned int*)g,
      (__attribute__((address_space(3))) unsigned int*)l, 16, 0, 0);
}

// ---------------------------------------------------------------------------
// Kernel 0: compress drop_mask into a bitmask. (v9, unchanged)
// ---------------------------------------------------------------------------
__global__ __launch_bounds__(256) void maskpack_kernel(
    const void* __restrict__ mask, unsigned long long* __restrict__ bm) {
  const int t = threadIdx.x, lane = t & 63, w = t >> 6;
  const int r = blockIdx.x + (w << 11);  // grid 2048 -> rows r, r+2048, ...
  const unsigned int* md = (const unsigned int*)mask;
  bool a01 = true, af = true;
#pragma unroll
  for (int k = 0; k < 4; ++k) {
    unsigned int v = md[lane + 64 * k];
    a01 = a01 && (v <= 1u);
    af = af && (v == 0u || v == 0x3F800000u);
  }
  const bool dword_mode = __all(a01) || __all(af);
  unsigned long long* out = bm + (size_t)r * 128;
  if (dword_mode) {
    const unsigned int* mk = (const unsigned int*)mask + (size_t)r * NT;
    const int iters = (r >> 8) + 1;  // 256 cols per iteration
    for (int it = 0; it < iters; ++it) {
      const int j0 = it * 256;
      unsigned int v0 = mk[j0 + lane];
      unsigned int v1 = mk[j0 + 64 + lane];
      unsigned int v2 = mk[j0 + 128 + lane];
      unsigned int v3 = mk[j0 + 192 + lane];
      unsigned long long b0 = __ballot(v0 != 0u);
      unsigned long long b1 = __ballot(v1 != 0u);
      unsigned long long b2 = __ballot(v2 != 0u);
      unsigned long long b3 = __ballot(v3 != 0u);
      if (lane == 0) {
        out[(j0 >> 6) + 0] = b0;
        out[(j0 >> 6) + 1] = b1;
        out[(j0 >> 6) + 2] = b2;
        out[(j0 >> 6) + 3] = b3;
      }
    }
  } else {
    const unsigned char* mk = (const unsigned char*)mask + (size_t)r * NT;
    unsigned short* outs = (unsigned short*)out;
    const int iters = (r >> 10) + 1;  // 1024 cols per wave-iteration
    for (int it = 0; it < iters; ++it) {
      const uint4 d = *(const uint4*)(mk + it * 1024 + lane * 16);
      unsigned int dws[4] = {d.x, d.y, d.z, d.w};
      unsigned int m16 = 0;
#pragma unroll
      for (int k = 0; k < 4; ++k) {
        unsigned int x = dws[k];
        x |= x >> 4;
        x |= x >> 2;
        x |= x >> 1;
        x &= 0x01010101u;
        m16 |= ((x * 0x01020408u) >> 24) << (4 * k);
      }
      outs[it * 64 + lane] = (unsigned short)m16;  // 128 B/wave, coalesced
    }
  }
}

// ---------------------------------------------------------------------------
// Kernel 1: QKV projection. (unchanged)
// ---------------------------------------------------------------------------
__global__ __launch_bounds__(256) void proj_kernel(
    const float* __restrict__ X, const float* __restrict__ Wq,
    const float* __restrict__ Wk, const float* __restrict__ Wv,
    unsigned short* __restrict__ Qs, unsigned short* __restrict__ Kb,
    unsigned short* __restrict__ Vt) {
  __shared__ __align__(16) unsigned short Xs[64 * 256];
  __shared__ __align__(16) unsigned short Ws[64 * 256];
  __shared__ float Tr[4][32 * 33];
  const int ib = blockIdx.x, mat = blockIdx.y;
  const float* W = (mat == 0) ? Wq : (mat == 1) ? Wk : Wv;
  // mat 0: fold softmax scale (1/sqrt(256)) and log2(e); mat 2: fold dropout 2x
  const float wscale = (mat == 0) ? 0.09016844005556021f : (mat == 2 ? 2.0f : 1.0f);
  const int t = threadIdx.x;
  const int lane = t & 63, w = t >> 6;
  const int m = lane & 31, half = lane >> 5;
  const int i0 = ib * 64;
#pragma unroll
  for (int cc = 0; cc < 8; ++cc) {
    int chunk = t + 256 * cc;
    int rr = chunk >> 5, c = chunk & 31;
    const float4* src = (const float4*)(X + (size_t)(i0 + rr) * 256 + c * 8);
    float4 f0 = src[0], f1 = src[1];
    bf16x8 v;
    v[0] = (__bf16)f0.x; v[1] = (__bf16)f0.y; v[2] = (__bf16)f0.z; v[3] = (__bf16)f0.w;
    v[4] = (__bf16)f1.x; v[5] = (__bf16)f1.y; v[6] = (__bf16)f1.z; v[7] = (__bf16)f1.w;
    *(bf16x8*)&Xs[(rr * 32 + (c ^ (rr & 31))) * 8] = v;
  }
  const int wr = w >> 1, wc = w & 1;
  for (int cb = 0; cb < 4; ++cb) {
    __syncthreads();
#pragma unroll
    for (int cc = 0; cc < 8; ++cc) {
      int chunk = t + 256 * cc;
      int rr = chunk >> 5, c = chunk & 31;
      const float4* src = (const float4*)(W + (size_t)(cb * 64 + rr) * 256 + c * 8);
      float4 f0 = src[0], f1 = src[1];
      bf16x8 v;
      v[0] = (__bf16)(f0.x * wscale); v[1] = (__bf16)(f0.y * wscale);
      v[2] = (__bf16)(f0.z * wscale); v[3] = (__bf16)(f0.w * wscale);
      v[4] = (__bf16)(f1.x * wscale); v[5] = (__bf16)(f1.y * wscale);
      v[6] = (__bf16)(f1.z * wscale); v[7] = (__bf16)(f1.w * wscale);
      *(bf16x8*)&Ws[(rr * 32 + (c ^ (rr & 31))) * 8] = v;
    }
    __syncthreads();
    f32x16 acc = {};
    const int ar = 32 * wr + m;
    const int br = 32 * wc + m;
#pragma unroll
    for (int st = 0; st < 16; ++st) {
      int kc = st * 2 + half;
      bf16x8 a = *(const bf16x8*)&Xs[(ar * 32 + (kc ^ (ar & 31))) * 8];
      bf16x8 b = *(const bf16x8*)&Ws[(br * 32 + (kc ^ (br & 31))) * 8];
      acc = MFMA32(a, b, acc);
    }
    if (mat < 2) {
      unsigned short* O = mat ? Kb : Qs;
#pragma unroll
      for (int r = 0; r < 16; ++r) {
        int row = i0 + 32 * wr + (r & 3) + 8 * (r >> 2) + 4 * half;
        int col = cb * 64 + 32 * wc + m;
        O[(size_t)row * DM + col] = f2bf_bits(acc[r]);
      }
    } else {
      float* T = Tr[w];
#pragma unroll
      for (int r = 0; r < 16; ++r) {
        int rl = (r & 3) + 8 * (r >> 2) + 4 * half;
        T[m * 33 + rl] = acc[r];
      }
      asm volatile("s_waitcnt lgkmcnt(0)" ::: "memory");
#pragma unroll
      for (int q = 0; q < 16; ++q) {
        int dl = 2 * q + half;
        float val = T[dl * 33 + m];
        Vt[(size_t)(cb * 64 + 32 * wc + dl) * NT + i0 + 32 * wr + m] = f2bf_bits(val);
      }
      asm volatile("s_waitcnt lgkmcnt(0)" ::: "memory");
    }
  }
}

// ---------------------------------------------------------------------------
// Dropout-select + bf16-pack + 2-stage 4-lane shuffle butterfly building the
// P^T B-fragment for one 32-column group. (unchanged helper)
// ---------------------------------------------------------------------------
static __device__ __forceinline__ bf16x8 pack_butterfly(const f32x4 sA, const f32x4 sB,
                                                        unsigned int bits, int q) {
  unsigned int A0, A1, B0, B1;
  {
    unsigned int bbA = bits >> (q * 4);
    unsigned int bbB = bits >> (16 + q * 4);
    float a0 = (bbA & 1u) ? sA[0] : 0.f, a1 = (bbA & 2u) ? sA[1] : 0.f;
    float a2 = (bbA & 4u) ? sA[2] : 0.f, a3 = (bbA & 8u) ? sA[3] : 0.f;
    float b0 = (bbB & 1u) ? sB[0] : 0.f, b1 = (bbB & 2u) ? sB[1] : 0.f;
    float b2 = (bbB & 4u) ? sB[2] : 0.f, b3 = (bbB & 8u) ? sB[3] : 0.f;
    A0 = (unsigned)f2bf_bits(a0) | ((unsigned)f2bf_bits(a1) << 16);
    A1 = (unsigned)f2bf_bits(a2) | ((unsigned)f2bf_bits(a3) << 16);
    B0 = (unsigned)f2bf_bits(b0) | ((unsigned)f2bf_bits(b1) << 16);
    B1 = (unsigned)f2bf_bits(b2) | ((unsigned)f2bf_bits(b3) << 16);
  }
  unsigned int own0 = (q & 2) ? B0 : A0, own1 = (q & 2) ? B1 : A1;
  unsigned int t0 = (q & 2) ? A0 : B0, t1 = (q & 2) ? A1 : B1;
  unsigned int r10 = __shfl_xor(t0, 32);
  unsigned int r11 = __shfl_xor(t1, 32);
  const bool selOwn = ((q ^ (q >> 1)) & 1) != 0;
  unsigned int s20 = selOwn ? own0 : r10;
  unsigned int s21 = selOwn ? own1 : r11;
  unsigned int r20 = __shfl_xor(s20, 16);
  unsigned int r21 = __shfl_xor(s21, 16);
  unsigned int lo0 = (q == 0) ? A0 : (q == 2) ? r10 : r20;
  unsigned int lo1 = (q == 0) ? A1 : (q == 2) ? r11 : r21;
  unsigned int hi0 = (q == 3) ? B0 : (q == 1) ? r10 : r20;
  unsigned int hi1 = (q == 3) ? B1 : (q == 1) ? r11 : r21;
  return __builtin_bit_cast(bf16x8, (u32x4){lo0, lo1, hi0, hi1});
}

// ---------------------------------------------------------------------------
// Kernel 2: flash attention, causal, post-softmax dropout (x2 folded into Vt).
// v19 = v18 (seg-band XCD remap, kept: K/V L2-resident, 1 MB/XCD) + V
// de-staged from LDS. Mechanism: after v18, V^T is served by L2, so staging
// it through LDS (and draining that DMA at every barrier) is pure overhead
// (guide common-mistake #7). Dropping Vsh:
//  1. LDS 64 -> 32 KiB ==> 3 blocks/CU (12 waves/CU, was 8): +50% latency
//     cover. __launch_bounds__(256,3) (~170 VGPR cap, room for V loads).
//  2. The mid-loop barrier now only protects Ksh (only QK^T reads LDS), so
//     it moves UP to right after the QK MFMAs, and STAGE(jb+1) issues right
//     after it: next-tile K DMA overlaps the whole softmax+butterfly+PV
//     phase (~500+ cyc) instead of nothing. Top-of-loop drain ~free.
//  3. V DMA disappears from the drain path; PV A-frags are global loads
//     (per instruction: 16 x 64 contiguous bytes, L2-friendly) whose latency
//     interleaves with the PV MFMA stream.
// Lane mapping (16x16x32): m=lane&15, q=lane>>4.
//   A[m][q*8+j], B[q*8+j][m], D[q*4+reg][m].
// ---------------------------------------------------------------------------
__global__ __launch_bounds__(256, 3) void flash_kernel(
    const unsigned short* __restrict__ Qs, const unsigned short* __restrict__ Kg,
    const unsigned short* __restrict__ Vtg, const unsigned long long* __restrict__ bm,
    float* __restrict__ ml_out, unsigned short* __restrict__ acc_out) {
  __shared__ __align__(16) unsigned short Ksh[64 * 256];   // 32 KiB (K only)
  // seg-band XCD remap (v18): XCD x owns segs {x, 15-x}; 136 blocks and 1032
  // tiles per XCD (exactly balanced); per-XCD K/V working set ~1 MB.
  const int p = blockIdx.x + 128 * blockIdx.y;   // HW dispatch-linear id
  const int x = p & 7, k = p >> 3;
  const int c0 = 128 - 8 * x;
  int ib, seg;
  if (k < c0) {
    seg = x;
    ib = 8 * x + k;
  } else if (k - c0 < 8 + 8 * x) {
    seg = 15 - x;
    ib = (120 - 8 * x) + (k - c0);
  } else {
    return;
  }
  const int jb_end = ib + 1;          // 64-col tiles needed for this row block
  const int jb0 = seg * 8;            // 8 tiles of 64 per segment
  if (jb0 >= jb_end) return;          // (never taken under the remap; kept)
  const int jb1 = (jb0 + 8 < jb_end) ? jb0 + 8 : jb_end;
  const int t = threadIdx.x, lane = t & 63, w = t >> 6;
  const int m = lane & 15, q = lane >> 4;
  const int i0 = ib * 64, rw0 = i0 + 16 * w;
  const int myrow = rw0 + m;

  // Q B-fragments, register resident (16 rows x 256 k per wave -> 32 VGPRs)
  bf16x8 qf[8];
  {
    const unsigned short* qp = Qs + (size_t)myrow * DM + q * 8;
#pragma unroll
    for (int st = 0; st < 8; ++st) qf[st] = *(const bf16x8*)(qp + st * 32);
  }
  f32x4 oacc[16] = {};          // O^T: d = ct*16 + q*4 + r, row i = myrow
  float mrun = -1e30f, lrun = 0.f;

#define STAGE(JB)                                                             \
  {                                                                           \
    const int j64_ = (JB) * 64;                                               \
    _Pragma("unroll") for (int i_ = 0; i_ < 8; ++i_) {                        \
      int chunk = t + 256 * i_;                                               \
      int row = chunk >> 5, slot = chunk & 31;                                \
      gload_lds16(Kg + (size_t)(j64_ + row) * DM + (slot ^ (row & 31)) * 8,   \
                  Ksh + (size_t)chunk * 8);                                   \
    }                                                                         \
  }

  STAGE(jb0)
  unsigned long long bits = bm[(size_t)myrow * 128 + jb0];  // u64 word = 64 cols
  for (int jb = jb0; jb < jb1; ++jb) {
    const int j64 = jb * 64;
    __syncthreads();  // K tile jb resident (drains this wave's K DMA; cheap:
                      // issued one full softmax+PV phase ago)
    const bool active = (j64 <= rw0 + 15);
    f32x4 s[4] = {};
    if (active) {
      // S^T = K Q^T: 4 j-tiles of 16. Lane holds S[myrow][j64+ct*16+q*4+r].
#pragma unroll
      for (int st = 0; st < 8; ++st) {
        int kc = st * 4 + q;
#pragma unroll
        for (int ct = 0; ct < 4; ++ct) {
          int jr = ct * 16 + m;
          bf16x8 a = *(const bf16x8*)&Ksh[(jr * 32 + (kc ^ (jr & 31))) * 8];
          s[ct] = MFMA16(a, qf[st], s[ct]);
        }
      }
    }
    __syncthreads();  // all waves done reading Ksh(jb)
    unsigned long long bits_n = 0;
    if (jb + 1 < jb1) {
      STAGE(jb + 1)   // K DMA for jb+1 overlaps the softmax+PV below
      bits_n = bm[(size_t)myrow * 128 + jb + 1];
    }
    if (active) {
      // causal mask
      if (j64 + 63 > rw0) {
#pragma unroll
        for (int ct = 0; ct < 4; ++ct)
#pragma unroll
          for (int r = 0; r < 4; ++r)
            if (j64 + ct * 16 + q * 4 + r > myrow) s[ct][r] = NEG_INF;
      }
      // online softmax: row = lane (scalar state). Reduce across q-lanes only.
      float mx = fmaxf(fmaxf(fmaxf(s[0][0], s[0][1]), fmaxf(s[0][2], s[0][3])),
                       fmaxf(fmaxf(s[1][0], s[1][1]), fmaxf(s[1][2], s[1][3])));
      mx = fmaxf(mx, fmaxf(fmaxf(fmaxf(s[2][0], s[2][1]), fmaxf(s[2][2], s[2][3])),
                           fmaxf(fmaxf(s[3][0], s[3][1]), fmaxf(s[3][2], s[3][3]))));
      mx = fmaxf(mx, __shfl_xor(mx, 16));
      mx = fmaxf(mx, __shfl_xor(mx, 32));
      const float mn = fmaxf(mrun, mx);
#pragma unroll
      for (int ct = 0; ct < 4; ++ct)
#pragma unroll
        for (int r = 0; r < 4; ++r) s[ct][r] = exp2_fast(s[ct][r] - mn);
      float rs = ((s[0][0] + s[0][1]) + (s[0][2] + s[0][3])) +
                 ((s[1][0] + s[1][1]) + (s[1][2] + s[1][3])) +
                 ((s[2][0] + s[2][1]) + (s[2][2] + s[2][3])) +
                 ((s[3][0] + s[3][1]) + (s[3][2] + s[3][3]));
      rs += __shfl_xor(rs, 16);
      rs += __shfl_xor(rs, 32);
      if (__all(mn == mrun)) {
        lrun += rs;                  // running max unchanged: skip O rescale
      } else {
        float alpha = exp2_fast(mrun - mn);
        lrun = lrun * alpha + rs;
#pragma unroll
        for (int ct = 0; ct < 16; ++ct)
#pragma unroll
          for (int r = 0; r < 4; ++r) oacc[ct][r] *= alpha;
        mrun = mn;
      }
      // dropout + pack + butterfly, one 32-col group per P^T fragment
      bf16x8 pf0 = pack_butterfly(s[0], s[1], (unsigned int)bits, q);
      bf16x8 pf1 = pack_butterfly(s[2], s[3], (unsigned int)(bits >> 32), q);
      // O^T += V^T P^T: A-frags straight from global Vt (L2-resident).
      // Per instruction: lanes (m,q) read d = ct*16+m rows at j-octet q
      // (a0) / q+4 (a1): 16 groups of 64 contiguous bytes.
      const unsigned short* vb = Vtg + (size_t)m * NT + j64 + q * 8;
#pragma unroll
      for (int ct = 0; ct < 16; ++ct) {
        const unsigned short* vr = vb + (size_t)(ct * 16) * NT;
        bf16x8 a0 = *(const bf16x8*)(vr);
        bf16x8 a1 = *(const bf16x8*)(vr + 32);
        oacc[ct] = MFMA16(a0, pf0, oacc[ct]);
        oacc[ct] = MFMA16(a1, pf1, oacc[ct]);
      }
    }
    bits = bits_n;
  }
#undef STAGE
  // write segment partials. g = segment slot for (ib, seg). (v12 formula)
  const int a_ = ib >> 3, r_ = ib & 7;
  const int g = 4 * a_ * (a_ + 1) + r_ * (a_ + 1) + seg;
  if (q == 0) {
    float* mlb = ml_out + ((size_t)g * 64 + 16 * w + m) * 2;
    mlb[0] = mrun;
    mlb[1] = lrun;
  }
  unsigned short* ab = acc_out + ((size_t)g * 64 + 16 * w + m) * DM;
#pragma unroll
  for (int ct = 0; ct < 16; ++ct) {
    unsigned long long pk = 0;
#pragma unroll
    for (int r = 0; r < 4; ++r)
      pk |= (unsigned long long)f2bf_bits(oacc[ct][r]) << (16 * r);
    *(unsigned long long*)&ab[ct * 16 + q * 4] = pk;  // 8B contiguous quads
  }
}

// ---------------------------------------------------------------------------
// Kernel 3: combine segment partials. (v12 version, unchanged)
// ---------------------------------------------------------------------------
__global__ __launch_bounds__(256) void combine_kernel(
    const float* __restrict__ ml, const unsigned short* __restrict__ pacc,
    float* __restrict__ out) {
  const int t = threadIdx.x;
  const int row = blockIdx.x * 32 + (t >> 3);
  const int cg = (t & 7) * 32;
  const int ib = row >> 6, rib = row & 63;
  const int a = ib >> 3, r = ib & 7;
  const int g0 = 4 * a * (a + 1) + r * (a + 1);
  const int ns = a + 1;
  float M = -1e30f;
  for (int s = 0; s < ns; ++s) M = fmaxf(M, ml[((size_t)(g0 + s) * 64 + rib) * 2]);
  float Wd = 0.f;
  float acc[32];
#pragma unroll
  for (int j = 0; j < 32; ++j) acc[j] = 0.f;
  for (int s = 0; s < ns; ++s) {
    const float* mls = ml + ((size_t)(g0 + s) * 64 + rib) * 2;
    float wv = exp2_fast(mls[0] - M);
    Wd += wv * mls[1];
    const unsigned short* pa = pacc + ((size_t)(g0 + s) * 64 + rib) * DM + cg;
#pragma unroll
    for (int v4 = 0; v4 < 4; ++v4) {
      bf16x8 b = *(const bf16x8*)(pa + v4 * 8);
#pragma unroll
      for (int j = 0; j < 8; ++j) acc[v4 * 8 + j] += wv * (float)b[j];
    }
  }
  float inv = 1.0f / Wd;
#pragma unroll
  for (int j = 0; j < 32; ++j) out[(size_t)row * DM + cg + j] = acc[j] * inv;
}

// ---------------------------------------------------------------------------
extern "C" void kernel_launch(void* const* d_in, const int* in_sizes, int n_in,
                              void* d_out, int out_size, void* d_ws, size_t ws_size,
                              hipStream_t stream) {
  const float* X  = (const float*)d_in[0];
  const float* Wq = (const float*)d_in[1];
  const float* Wk = (const float*)d_in[2];
  const float* Wv = (const float*)d_in[3];
  const void* mask = d_in[4];
  float* out = (float*)d_out;

  char* ws = (char*)d_ws;
  unsigned short* Qs = (unsigned short*)(ws + 4096);
  unsigned short* Kb = Qs + (size_t)NT * DM;
  unsigned short* Vt = Kb + (size_t)NT * DM;
  float* ml = (float*)(Vt + (size_t)NT * DM);                 // 1088*64*2 f32
  unsigned short* pacc = (unsigned short*)(ml + (size_t)1088 * 64 * 2);
  unsigned long long* bmw = (unsigned long long*)((char*)pacc + (size_t)1088 * 64 * DM * 2);
  // total ws use: 4096 + 12 MiB + 544 KiB + 34 MiB + 8 MiB ~= 55 MiB

  maskpack_kernel<<<2048, 256, 0, stream>>>(mask, bmw);
  proj_kernel<<<dim3(128, 3), 256, 0, stream>>>(X, Wq, Wk, Wv, Qs, Kb, Vt);
  flash_kernel<<<dim3(128, 16), 256, 0, stream>>>(Qs, Kb, Vt, bmw, ml, pacc);
  combine_kernel<<<256, 256, 0, stream>>>(ml, pacc, out);
}

// Round 10
// 447.393 us; speedup vs baseline: 1.3097x; 1.3097x over previous
//
#include <hip/hip_runtime.h>

// Problem constants (N=8192 tokens, D=256 model dim, dropout p=0.5 -> keep scale 2.0)
#define NT 8192
#define DM 256

typedef float f32x16 __attribute__((ext_vector_type(16)));
typedef float f32x4 __attribute__((ext_vector_type(4)));
typedef __bf16 bf16x8 __attribute__((ext_vector_type(8)));
typedef unsigned int u32x4 __attribute__((ext_vector_type(4)));

#define MFMA32(a, b, c) __builtin_amdgcn_mfma_f32_32x32x16_bf16((a), (b), (c), 0, 0, 0)
#define MFMA16(a, b, c) __builtin_amdgcn_mfma_f32_16x16x32_bf16((a), (b), (c), 0, 0, 0)
#define NEG_INF (-__builtin_inff())

static __device__ __forceinline__ unsigned short f2bf_bits(float f) {
  return __builtin_bit_cast(unsigned short, (__bf16)f);
}
static __device__ __forceinline__ float exp2_fast(float x) {
  return __builtin_amdgcn_exp2f(x);
}
// async global->LDS, 16B per lane. LDS dest is wave-uniform base + lane*16.
static __device__ __forceinline__ void gload_lds16(const void* g, void* l) {
  __builtin_amdgcn_global_load_lds(
      (const __attribute__((address_space(1))) unsigned int*)g,
      (__attribute__((address_space(3))) unsigned int*)l, 16, 0, 0);
}

// ---------------------------------------------------------------------------
// Kernel 0: compress drop_mask into a bitmask. (v9, unchanged)
// ---------------------------------------------------------------------------
__global__ __launch_bounds__(256) void maskpack_kernel(
    const void* __restrict__ mask, unsigned long long* __restrict__ bm) {
  const int t = threadIdx.x, lane = t & 63, w = t >> 6;
  const int r = blockIdx.x + (w << 11);  // grid 2048 -> rows r, r+2048, ...
  const unsigned int* md = (const unsigned int*)mask;
  bool a01 = true, af = true;
#pragma unroll
  for (int k = 0; k < 4; ++k) {
    unsigned int v = md[lane + 64 * k];
    a01 = a01 && (v <= 1u);
    af = af && (v == 0u || v == 0x3F800000u);
  }
  const bool dword_mode = __all(a01) || __all(af);
  unsigned long long* out = bm + (size_t)r * 128;
  if (dword_mode) {
    const unsigned int* mk = (const unsigned int*)mask + (size_t)r * NT;
    const int iters = (r >> 8) + 1;  // 256 cols per iteration
    for (int it = 0; it < iters; ++it) {
      const int j0 = it * 256;
      unsigned int v0 = mk[j0 + lane];
      unsigned int v1 = mk[j0 + 64 + lane];
      unsigned int v2 = mk[j0 + 128 + lane];
      unsigned int v3 = mk[j0 + 192 + lane];
      unsigned long long b0 = __ballot(v0 != 0u);
      unsigned long long b1 = __ballot(v1 != 0u);
      unsigned long long b2 = __ballot(v2 != 0u);
      unsigned long long b3 = __ballot(v3 != 0u);
      if (lane == 0) {
        out[(j0 >> 6) + 0] = b0;
        out[(j0 >> 6) + 1] = b1;
        out[(j0 >> 6) + 2] = b2;
        out[(j0 >> 6) + 3] = b3;
      }
    }
  } else {
    const unsigned char* mk = (const unsigned char*)mask + (size_t)r * NT;
    unsigned short* outs = (unsigned short*)out;
    const int iters = (r >> 10) + 1;  // 1024 cols per wave-iteration
    for (int it = 0; it < iters; ++it) {
      const uint4 d = *(const uint4*)(mk + it * 1024 + lane * 16);
      unsigned int dws[4] = {d.x, d.y, d.z, d.w};
      unsigned int m16 = 0;
#pragma unroll
      for (int k = 0; k < 4; ++k) {
        unsigned int x = dws[k];
        x |= x >> 4;
        x |= x >> 2;
        x |= x >> 1;
        x &= 0x01010101u;
        m16 |= ((x * 0x01020408u) >> 24) << (4 * k);
      }
      outs[it * 64 + lane] = (unsigned short)m16;  // 128 B/wave, coalesced
    }
  }
}

// ---------------------------------------------------------------------------
// Kernel 1: QKV projection. v20: Tr transpose buffer f32 -> bf16.
// Rationale: LDS was Xs(32K)+Ws(32K)+Tr(16.9K) = 81.4 KiB > 80 KiB -> only
// 1 block/CU; 384 blocks over 256 CUs => half the CUs run 2 sequential
// blocks (span ~2x block time). Tr's consumer converts to bf16 anyway, so
// storing bf16 in Tr is bit-identical output and drops LDS to 72.5 KiB ->
// 2 blocks/CU. Bank behavior: 2B elems, stride 33 -> 2-way aliasing on both
// write (T[m*33+rl]) and read (T[dl*33+m]) patterns; 2-way is free (m136).
// ---------------------------------------------------------------------------
__global__ __launch_bounds__(256) void proj_kernel(
    const float* __restrict__ X, const float* __restrict__ Wq,
    const float* __restrict__ Wk, const float* __restrict__ Wv,
    unsigned short* __restrict__ Qs, unsigned short* __restrict__ Kb,
    unsigned short* __restrict__ Vt) {
  __shared__ __align__(16) unsigned short Xs[64 * 256];
  __shared__ __align__(16) unsigned short Ws[64 * 256];
  __shared__ unsigned short Tr[4][32 * 33];   // bf16 bits (8.45 KiB total)
  const int ib = blockIdx.x, mat = blockIdx.y;
  const float* W = (mat == 0) ? Wq : (mat == 1) ? Wk : Wv;
  // mat 0: fold softmax scale (1/sqrt(256)) and log2(e); mat 2: fold dropout 2x
  const float wscale = (mat == 0) ? 0.09016844005556021f : (mat == 2 ? 2.0f : 1.0f);
  const int t = threadIdx.x;
  const int lane = t & 63, w = t >> 6;
  const int m = lane & 31, half = lane >> 5;
  const int i0 = ib * 64;
#pragma unroll
  for (int cc = 0; cc < 8; ++cc) {
    int chunk = t + 256 * cc;
    int rr = chunk >> 5, c = chunk & 31;
    const float4* src = (const float4*)(X + (size_t)(i0 + rr) * 256 + c * 8);
    float4 f0 = src[0], f1 = src[1];
    bf16x8 v;
    v[0] = (__bf16)f0.x; v[1] = (__bf16)f0.y; v[2] = (__bf16)f0.z; v[3] = (__bf16)f0.w;
    v[4] = (__bf16)f1.x; v[5] = (__bf16)f1.y; v[6] = (__bf16)f1.z; v[7] = (__bf16)f1.w;
    *(bf16x8*)&Xs[(rr * 32 + (c ^ (rr & 31))) * 8] = v;
  }
  const int wr = w >> 1, wc = w & 1;
  for (int cb = 0; cb < 4; ++cb) {
    __syncthreads();
#pragma unroll
    for (int cc = 0; cc < 8; ++cc) {
      int chunk = t + 256 * cc;
      int rr = chunk >> 5, c = chunk & 31;
      const float4* src = (const float4*)(W + (size_t)(cb * 64 + rr) * 256 + c * 8);
      float4 f0 = src[0], f1 = src[1];
      bf16x8 v;
      v[0] = (__bf16)(f0.x * wscale); v[1] = (__bf16)(f0.y * wscale);
      v[2] = (__bf16)(f0.z * wscale); v[3] = (__bf16)(f0.w * wscale);
      v[4] = (__bf16)(f1.x * wscale); v[5] = (__bf16)(f1.y * wscale);
      v[6] = (__bf16)(f1.z * wscale); v[7] = (__bf16)(f1.w * wscale);
      *(bf16x8*)&Ws[(rr * 32 + (c ^ (rr & 31))) * 8] = v;
    }
    __syncthreads();
    f32x16 acc = {};
    const int ar = 32 * wr + m;
    const int br = 32 * wc + m;
#pragma unroll
    for (int st = 0; st < 16; ++st) {
      int kc = st * 2 + half;
      bf16x8 a = *(const bf16x8*)&Xs[(ar * 32 + (kc ^ (ar & 31))) * 8];
      bf16x8 b = *(const bf16x8*)&Ws[(br * 32 + (kc ^ (br & 31))) * 8];
      acc = MFMA32(a, b, acc);
    }
    if (mat < 2) {
      unsigned short* O = mat ? Kb : Qs;
#pragma unroll
      for (int r = 0; r < 16; ++r) {
        int row = i0 + 32 * wr + (r & 3) + 8 * (r >> 2) + 4 * half;
        int col = cb * 64 + 32 * wc + m;
        O[(size_t)row * DM + col] = f2bf_bits(acc[r]);
      }
    } else {
      unsigned short* T = Tr[w];
#pragma unroll
      for (int r = 0; r < 16; ++r) {
        int rl = (r & 3) + 8 * (r >> 2) + 4 * half;
        T[m * 33 + rl] = f2bf_bits(acc[r]);   // convert before LDS round-trip
      }
      asm volatile("s_waitcnt lgkmcnt(0)" ::: "memory");
#pragma unroll
      for (int q = 0; q < 16; ++q) {
        int dl = 2 * q + half;
        Vt[(size_t)(cb * 64 + 32 * wc + dl) * NT + i0 + 32 * wr + m] = T[dl * 33 + m];
      }
      asm volatile("s_waitcnt lgkmcnt(0)" ::: "memory");
    }
  }
}

// ---------------------------------------------------------------------------
// Dropout-select + bf16-pack + 2-stage 4-lane shuffle butterfly building the
// P^T B-fragment for one 32-column group. (unchanged helper)
// ---------------------------------------------------------------------------
static __device__ __forceinline__ bf16x8 pack_butterfly(const f32x4 sA, const f32x4 sB,
                                                        unsigned int bits, int q) {
  unsigned int A0, A1, B0, B1;
  {
    unsigned int bbA = bits >> (q * 4);
    unsigned int bbB = bits >> (16 + q * 4);
    float a0 = (bbA & 1u) ? sA[0] : 0.f, a1 = (bbA & 2u) ? sA[1] : 0.f;
    float a2 = (bbA & 4u) ? sA[2] : 0.f, a3 = (bbA & 8u) ? sA[3] : 0.f;
    float b0 = (bbB & 1u) ? sB[0] : 0.f, b1 = (bbB & 2u) ? sB[1] : 0.f;
    float b2 = (bbB & 4u) ? sB[2] : 0.f, b3 = (bbB & 8u) ? sB[3] : 0.f;
    A0 = (unsigned)f2bf_bits(a0) | ((unsigned)f2bf_bits(a1) << 16);
    A1 = (unsigned)f2bf_bits(a2) | ((unsigned)f2bf_bits(a3) << 16);
    B0 = (unsigned)f2bf_bits(b0) | ((unsigned)f2bf_bits(b1) << 16);
    B1 = (unsigned)f2bf_bits(b2) | ((unsigned)f2bf_bits(b3) << 16);
  }
  unsigned int own0 = (q & 2) ? B0 : A0, own1 = (q & 2) ? B1 : A1;
  unsigned int t0 = (q & 2) ? A0 : B0, t1 = (q & 2) ? A1 : B1;
  unsigned int r10 = __shfl_xor(t0, 32);
  unsigned int r11 = __shfl_xor(t1, 32);
  const bool selOwn = ((q ^ (q >> 1)) & 1) != 0;
  unsigned int s20 = selOwn ? own0 : r10;
  unsigned int s21 = selOwn ? own1 : r11;
  unsigned int r20 = __shfl_xor(s20, 16);
  unsigned int r21 = __shfl_xor(s21, 16);
  unsigned int lo0 = (q == 0) ? A0 : (q == 2) ? r10 : r20;
  unsigned int lo1 = (q == 0) ? A1 : (q == 2) ? r11 : r21;
  unsigned int hi0 = (q == 3) ? B0 : (q == 1) ? r10 : r20;
  unsigned int hi1 = (q == 3) ? B1 : (q == 1) ? r11 : r21;
  return __builtin_bit_cast(bf16x8, (u32x4){lo0, lo1, hi0, hi1});
}

// ---------------------------------------------------------------------------
// Kernel 2: flash attention, causal, post-softmax dropout (x2 folded into Vt).
// v18 exactly (KVBLK=64 single-buffer MFMA16 + seg-band XCD remap; best known
// at 453.5 us). v19's V-destage reverted: PV-from-global gather (16 scattered
// 64B segments/MFMA, 32 dependent L2 loads/tile) cost far more than the DMA
// drain it removed, despite FETCH 362->34 MB. K/V staging stays in LDS.
// Lane mapping (16x16x32): m=lane&15, q=lane>>4.
//   A[m][q*8+j], B[q*8+j][m], D[q*4+reg][m].
// ---------------------------------------------------------------------------
__global__ __launch_bounds__(256, 2) void flash_kernel(
    const unsigned short* __restrict__ Qs, const unsigned short* __restrict__ Kg,
    const unsigned short* __restrict__ Vtg, const unsigned long long* __restrict__ bm,
    float* __restrict__ ml_out, unsigned short* __restrict__ acc_out) {
  __shared__ __align__(16) unsigned short Ksh[64 * 256];   // 32 KiB
  __shared__ __align__(16) unsigned short Vsh[256 * 64];   // 32 KiB
  // seg-band XCD remap (v18): XCD x owns segs {x, 15-x}; 136 blocks and 1032
  // tiles per XCD (exactly balanced); per-XCD K/V working set ~1 MB.
  const int p = blockIdx.x + 128 * blockIdx.y;   // HW dispatch-linear id
  const int x = p & 7, k = p >> 3;
  const int c0 = 128 - 8 * x;
  int ib, seg;
  if (k < c0) {
    seg = x;
    ib = 8 * x + k;
  } else if (k - c0 < 8 + 8 * x) {
    seg = 15 - x;
    ib = (120 - 8 * x) + (k - c0);
  } else {
    return;
  }
  const int jb_end = ib + 1;          // 64-col tiles needed for this row block
  const int jb0 = seg * 8;            // 8 tiles of 64 per segment
  if (jb0 >= jb_end) return;          // (never taken under the remap; kept)
  const int jb1 = (jb0 + 8 < jb_end) ? jb0 + 8 : jb_end;
  const int t = threadIdx.x, lane = t & 63, w = t >> 6;
  const int m = lane & 15, q = lane >> 4;
  const int i0 = ib * 64, rw0 = i0 + 16 * w;
  const int myrow = rw0 + m;

  // Q B-fragments, register resident (16 rows x 256 k per wave -> 32 VGPRs)
  bf16x8 qf[8];
  {
    const unsigned short* qp = Qs + (size_t)myrow * DM + q * 8;
#pragma unroll
    for (int st = 0; st < 8; ++st) qf[st] = *(const bf16x8*)(qp + st * 32);
  }
  f32x4 oacc[16] = {};          // O^T: d = ct*16 + q*4 + r, row i = myrow
  float mrun = -1e30f, lrun = 0.f;

#define STAGE(JB)                                                             \
  {                                                                           \
    const int j64_ = (JB) * 64;                                               \
    _Pragma("unroll") for (int i_ = 0; i_ < 8; ++i_) {                        \
      int chunk = t + 256 * i_;                                               \
      int row = chunk >> 5, slot = chunk & 31;                                \
      gload_lds16(Kg + (size_t)(j64_ + row) * DM + (slot ^ (row & 31)) * 8,   \
                  Ksh + (size_t)chunk * 8);                                   \
    }                                                                         \
    _Pragma("unroll") for (int i_ = 0; i_ < 8; ++i_) {                        \
      int chunk = t + 256 * i_;                                               \
      int d_ = chunk >> 3, slot = chunk & 7;                                  \
      gload_lds16(Vtg + (size_t)d_ * NT + j64_ + (slot ^ (d_ & 7)) * 8,       \
                  Vsh + (size_t)chunk * 8);                                   \
    }                                                                         \
  }

  STAGE(jb0)
  unsigned long long bits = bm[(size_t)myrow * 128 + jb0];  // u64 word = 64 cols
  for (int jb = jb0; jb < jb1; ++jb) {
    const int j64 = jb * 64;
    __syncthreads();  // drains tile-jb DMA (vmcnt 0) + all waves arrived
    if (j64 <= rw0 + 15) {  // wave has at least one unmasked (row, col) pair
      // S^T = K Q^T: 4 j-tiles of 16. Lane holds S[myrow][j64+ct*16+q*4+r].
      f32x4 s[4] = {};
#pragma unroll
      for (int st = 0; st < 8; ++st) {
        int kc = st * 4 + q;
#pragma unroll
        for (int ct = 0; ct < 4; ++ct) {
          int jr = ct * 16 + m;
          bf16x8 a = *(const bf16x8*)&Ksh[(jr * 32 + (kc ^ (jr & 31))) * 8];
          s[ct] = MFMA16(a, qf[st], s[ct]);
        }
      }
      // causal mask
      if (j64 + 63 > rw0) {
#pragma unroll
        for (int ct = 0; ct < 4; ++ct)
#pragma unroll
          for (int r = 0; r < 4; ++r)
            if (j64 + ct * 16 + q * 4 + r > myrow) s[ct][r] = NEG_INF;
      }
      // online softmax: row = lane (scalar state). Reduce across q-lanes only.
      float mx = fmaxf(fmaxf(fmaxf(s[0][0], s[0][1]), fmaxf(s[0][2], s[0][3])),
                       fmaxf(fmaxf(s[1][0], s[1][1]), fmaxf(s[1][2], s[1][3])));
      mx = fmaxf(mx, fmaxf(fmaxf(fmaxf(s[2][0], s[2][1]), fmaxf(s[2][2], s[2][3])),
                           fmaxf(fmaxf(s[3][0], s[3][1]), fmaxf(s[3][2], s[3][3]))));
      mx = fmaxf(mx, __shfl_xor(mx, 16));
      mx = fmaxf(mx, __shfl_xor(mx, 32));
      const float mn = fmaxf(mrun, mx);
#pragma unroll
      for (int ct = 0; ct < 4; ++ct)
#pragma unroll
        for (int r = 0; r < 4; ++r) s[ct][r] = exp2_fast(s[ct][r] - mn);
      float rs = ((s[0][0] + s[0][1]) + (s[0][2] + s[0][3])) +
                 ((s[1][0] + s[1][1]) + (s[1][2] + s[1][3])) +
                 ((s[2][0] + s[2][1]) + (s[2][2] + s[2][3])) +
                 ((s[3][0] + s[3][1]) + (s[3][2] + s[3][3]));
      rs += __shfl_xor(rs, 16);
      rs += __shfl_xor(rs, 32);
      if (__all(mn == mrun)) {
        lrun += rs;                  // running max unchanged: skip O rescale
      } else {
        float alpha = exp2_fast(mrun - mn);
        lrun = lrun * alpha + rs;
#pragma unroll
        for (int ct = 0; ct < 16; ++ct)
#pragma unroll
          for (int r = 0; r < 4; ++r) oacc[ct][r] *= alpha;
        mrun = mn;
      }
      // dropout + pack + butterfly, one 32-col group per P^T fragment
      bf16x8 pf0 = pack_butterfly(s[0], s[1], (unsigned int)bits, q);
      bf16x8 pf1 = pack_butterfly(s[2], s[3], (unsigned int)(bits >> 32), q);
      // O^T += V^T P^T: A = Vt rows (d = ct*16+m), k = 64 j's (two MFMA/ct)
#pragma unroll
      for (int ct = 0; ct < 16; ++ct) {
        int d = ct * 16 + m;
        bf16x8 a0 = *(const bf16x8*)&Vsh[(d * 8 + (q ^ (d & 7))) * 8];
        bf16x8 a1 = *(const bf16x8*)&Vsh[(d * 8 + ((q + 4) ^ (d & 7))) * 8];
        oacc[ct] = MFMA16(a0, pf0, oacc[ct]);
        oacc[ct] = MFMA16(a1, pf1, oacc[ct]);
      }
    }
    __syncthreads();  // all waves done reading K/V(jb)
    if (jb + 1 < jb1) {
      STAGE(jb + 1)
      bits = bm[(size_t)myrow * 128 + jb + 1];
    }
  }
#undef STAGE
  // write segment partials. g = segment slot for (ib, seg). (v12 formula)
  const int a_ = ib >> 3, r_ = ib & 7;
  const int g = 4 * a_ * (a_ + 1) + r_ * (a_ + 1) + seg;
  if (q == 0) {
    float* mlb = ml_out + ((size_t)g * 64 + 16 * w + m) * 2;
    mlb[0] = mrun;
    mlb[1] = lrun;
  }
  unsigned short* ab = acc_out + ((size_t)g * 64 + 16 * w + m) * DM;
#pragma unroll
  for (int ct = 0; ct < 16; ++ct) {
    unsigned long long pk = 0;
#pragma unroll
    for (int r = 0; r < 4; ++r)
      pk |= (unsigned long long)f2bf_bits(oacc[ct][r]) << (16 * r);
    *(unsigned long long*)&ab[ct * 16 + q * 4] = pk;  // 8B contiguous quads
  }
}

// ---------------------------------------------------------------------------
// Kernel 3: combine segment partials. (v12 version, unchanged)
// ---------------------------------------------------------------------------
__global__ __launch_bounds__(256) void combine_kernel(
    const float* __restrict__ ml, const unsigned short* __restrict__ pacc,
    float* __restrict__ out) {
  const int t = threadIdx.x;
  const int row = blockIdx.x * 32 + (t >> 3);
  const int cg = (t & 7) * 32;
  const int ib = row >> 6, rib = row & 63;
  const int a = ib >> 3, r = ib & 7;
  const int g0 = 4 * a * (a + 1) + r * (a + 1);
  const int ns = a + 1;
  float M = -1e30f;
  for (int s = 0; s < ns; ++s) M = fmaxf(M, ml[((size_t)(g0 + s) * 64 + rib) * 2]);
  float Wd = 0.f;
  float acc[32];
#pragma unroll
  for (int j = 0; j < 32; ++j) acc[j] = 0.f;
  for (int s = 0; s < ns; ++s) {
    const float* mls = ml + ((size_t)(g0 + s) * 64 + rib) * 2;
    float wv = exp2_fast(mls[0] - M);
    Wd += wv * mls[1];
    const unsigned short* pa = pacc + ((size_t)(g0 + s) * 64 + rib) * DM + cg;
#pragma unroll
    for (int v4 = 0; v4 < 4; ++v4) {
      bf16x8 b = *(const bf16x8*)(pa + v4 * 8);
#pragma unroll
      for (int j = 0; j < 8; ++j) acc[v4 * 8 + j] += wv * (float)b[j];
    }
  }
  float inv = 1.0f / Wd;
#pragma unroll
  for (int j = 0; j < 32; ++j) out[(size_t)row * DM + cg + j] = acc[j] * inv;
}

// ---------------------------------------------------------------------------
extern "C" void kernel_launch(void* const* d_in, const int* in_sizes, int n_in,
                              void* d_out, int out_size, void* d_ws, size_t ws_size,
                              hipStream_t stream) {
  const float* X  = (const float*)d_in[0];
  const float* Wq = (const float*)d_in[1];
  const float* Wk = (const float*)d_in[2];
  const float* Wv = (const float*)d_in[3];
  const void* mask = d_in[4];
  float* out = (float*)d_out;

  char* ws = (char*)d_ws;
  unsigned short* Qs = (unsigned short*)(ws + 4096);
  unsigned short* Kb = Qs + (size_t)NT * DM;
  unsigned short* Vt = Kb + (size_t)NT * DM;
  float* ml = (float*)(Vt + (size_t)NT * DM);                 // 1088*64*2 f32
  unsigned short* pacc = (unsigned short*)(ml + (size_t)1088 * 64 * 2);
  unsigned long long* bmw = (unsigned long long*)((char*)pacc + (size_t)1088 * 64 * DM * 2);
  // total ws use: 4096 + 12 MiB + 544 KiB + 34 MiB + 8 MiB ~= 55 MiB

  maskpack_kernel<<<2048, 256, 0, stream>>>(mask, bmw);
  proj_kernel<<<dim3(128, 3), 256, 0, stream>>>(X, Wq, Wk, Wv, Qs, Kb, Vt);
  flash_kernel<<<dim3(128, 16), 256, 0, stream>>>(Qs, Kb, Vt, bmw, ml, pacc);
  combine_kernel<<<256, 256, 0, stream>>>(ml, pacc, out);
}